// Round 1
// baseline (73.365 us; speedup 1.0000x reference)
//
#include <hip/hip_runtime.h>

// out[b,i,h] = m_i * (1/denom_b) * sum_{j valid} sigmoid(zc[b,i,h] + zy[b,j,h])
// with zc = z@Wc^T+bc, zy = z@Wy^T+by.
// Key identity: sigmoid(a+b) = 1 / (1 + e^{-a} * e^{-b})  -> precompute
// E=e^{-zc} (registers), F=e^{-zy} (LDS); inner loop = fma + v_rcp + add.

#define LOG2E 1.4426950408889634f

constexpr int NV = 48;
constexpr int H  = 32;
constexpr int BLOCK = 256;

__global__ void OptLinker_attn_kernel(const float* __restrict__ z,
                                      const float* __restrict__ Wc,
                                      const float* __restrict__ bc,
                                      const float* __restrict__ Wy,
                                      const float* __restrict__ by,
                                      const int*   __restrict__ mask,
                                      float* __restrict__ out)
{
    __shared__ float z_s[NV * H];       // 6 KB, graph's z tile
    __shared__ float wc_s[H * 33];      // padded: bank (h+k)%32, conflict-free
    __shared__ float wy_s[H * 33];
    __shared__ float bc_s[H], by_s[H];
    __shared__ float F_s[NV * H];       // e^{-zy[j,h]}
    __shared__ int   validIdx[NV];
    __shared__ int   m_s[NV];
    __shared__ int   nvalid_s;

    const int b   = blockIdx.x;
    const int tid = threadIdx.x;
    const int h   = tid & 31;           // lane's H column
    const int i0  = tid >> 5;           // 0..7 node sub-row

    // ---- stage 0: global -> LDS staging (all coalesced) ----
    const float* zb = z + (size_t)b * (NV * H);
    #pragma unroll
    for (int idx = tid; idx < NV * H; idx += BLOCK) z_s[idx] = zb[idx];
    for (int idx = tid; idx < H * H; idx += BLOCK) {
        int r = idx >> 5, c = idx & 31;
        wc_s[r * 33 + c] = Wc[idx];     // Wc[h][k] at wc_s[h*33+k]
        wy_s[r * 33 + c] = Wy[idx];
    }
    if (tid < H) { bc_s[tid] = bc[tid]; by_s[tid] = by[tid]; }

    // wave 0: mask, denom, ballot-compacted valid-j list
    if (tid < 64) {
        int m = (tid < NV) ? mask[b * NV + tid] : 0;
        if (tid < NV) m_s[tid] = m;
        unsigned long long bal = __ballot(m != 0);
        if (m != 0) {
            int pos = __popcll(bal & ((1ull << tid) - 1ull));
            validIdx[pos] = tid;
        }
        if (tid == 0) nvalid_s = __popcll(bal);
    }
    __syncthreads();

    // ---- stage A: zc, zy for this thread's 6 nodes; E in regs, F in LDS ----
    float E[6];
    #pragma unroll
    for (int it = 0; it < 6; ++it) {
        const int i = i0 + it * 8;      // covers 0..47
        float accC = bc_s[h], accY = by_s[h];
        #pragma unroll
        for (int k = 0; k < H; ++k) {
            float zv = z_s[i * H + k];              // broadcast within half-wave
            accC = fmaf(zv, wc_s[h * 33 + k], accC); // conflict-free
            accY = fmaf(zv, wy_s[h * 33 + k], accY);
        }
        E[it] = __builtin_amdgcn_exp2f(-accC * LOG2E);        // e^{-zc}
        F_s[i * H + h] = __builtin_amdgcn_exp2f(-accY * LOG2E); // e^{-zy}
    }
    __syncthreads();

    // ---- stage B: sum over valid j; 6 independent chains hide rcp latency ----
    const int nvalid = nvalid_s;
    float acc[6] = {0.f, 0.f, 0.f, 0.f, 0.f, 0.f};
    for (int v = 0; v < nvalid; ++v) {
        const int jv = validIdx[v];      // broadcast LDS read
        const float f = F_s[jv * H + h]; // broadcast across half-waves
        #pragma unroll
        for (int it = 0; it < 6; ++it)
            acc[it] += __builtin_amdgcn_rcpf(fmaf(E[it], f, 1.0f));
    }

    // ---- epilogue: scale by 1/denom, zero invalid rows, coalesced store ----
    const float rden = __builtin_amdgcn_rcpf((float)nvalid);
    float* ob = out + (size_t)b * (NV * H);
    #pragma unroll
    for (int it = 0; it < 6; ++it) {
        const int i = i0 + it * 8;
        ob[i * H + h] = m_s[i] ? acc[it] * rden : 0.0f;
    }
}

extern "C" void kernel_launch(void* const* d_in, const int* in_sizes, int n_in,
                              void* d_out, int out_size, void* d_ws, size_t ws_size,
                              hipStream_t stream) {
    const float* z    = (const float*)d_in[0];
    const float* Wc   = (const float*)d_in[1];
    const float* bc   = (const float*)d_in[2];
    const float* Wy   = (const float*)d_in[3];
    const float* by   = (const float*)d_in[4];
    const int*   mask = (const int*)d_in[5];
    float* out = (float*)d_out;

    const int ngraph = in_sizes[0] / (NV * H);   // 512
    OptLinker_attn_kernel<<<ngraph, BLOCK, 0, stream>>>(z, Wc, bc, Wy, by, mask, out);
}

// Round 2
// 21.668 us; speedup vs baseline: 3.3859x; 3.3859x over previous
//
#include <hip/hip_runtime.h>

// out[b,i,h] = m_i * (1/denom_b) * sum_{j valid} sigmoid(zc[b,i,h] + zy[b,j,h])
// zc = z@Wc^T+bc, zy = z@Wy^T+by.
// sigmoid(a+b) = 1/(1 + e^{-a} e^{-b}):  E=e^{-zc} (regs), F=e^{-zy} (LDS);
// inner loop = fma + v_rcp + add. W rows live in REGISTERS (each lane always
// uses row h), z tile in LDS read as float4. Valid-j set = 64-bit ballot mask.

#define LOG2E 1.4426950408889634f

constexpr int NV = 48;
constexpr int H  = 32;
constexpr int BLOCK = 512;   // 8 waves; thread = (i0 in 0..15, h in 0..31)

__global__ __launch_bounds__(BLOCK, 4)
void OptLinker_attn_kernel(const float* __restrict__ z,
                           const float* __restrict__ Wc,
                           const float* __restrict__ bc,
                           const float* __restrict__ Wy,
                           const float* __restrict__ by,
                           const int*   __restrict__ mask,
                           float* __restrict__ out)
{
    __shared__ float z_s[NV * H];   // 6 KB, stride 32 floats (16B-aligned rows)
    __shared__ float F_s[NV * H];   // e^{-zy[j,h]}

    const int b   = blockIdx.x;
    const int tid = threadIdx.x;
    const int h   = tid & 31;       // lane's H column
    const int i0  = tid >> 5;       // 0..15; rows i0, i0+16, i0+32

    // ---- stage 0a: z tile -> LDS (float4, coalesced) ----
    const float4* zb4 = (const float4*)(z + (size_t)b * (NV * H));
    float4* zs4 = (float4*)z_s;
    for (int idx = tid; idx < (NV * H) / 4; idx += BLOCK) zs4[idx] = zb4[idx];

    // ---- stage 0b: W rows h -> registers (L1-hot after first block) ----
    const float4* wcv = (const float4*)Wc;
    const float4* wyv = (const float4*)Wy;
    float4 wc_r[8], wy_r[8];
    #pragma unroll
    for (int q = 0; q < 8; ++q) { wc_r[q] = wcv[h * 8 + q]; wy_r[q] = wyv[h * 8 + q]; }
    const float bcv = bc[h], byv = by[h];

    // ---- stage 0c: valid-j bitmask via ballot (no LDS, no extra sync) ----
    const int lane = tid & 63;
    const int mv = (lane < NV) ? mask[b * NV + lane] : 0;
    const unsigned long long bits = __ballot(mv != 0);
    const int nvalid = __popcll(bits);

    __syncthreads();   // z_s ready

    // ---- stage A: zc, zy for 3 rows; E in regs, F to LDS ----
    float E[3];
    #pragma unroll
    for (int it = 0; it < 3; ++it) {
        const int i = i0 + it * 16;
        float accC = bcv, accY = byv;
        const float4* zr = (const float4*)(z_s + i * H);
        #pragma unroll
        for (int q = 0; q < 8; ++q) {
            const float4 zv = zr[q];   // ds_read_b128, broadcast per half-wave
            accC = fmaf(zv.x, wc_r[q].x, accC);
            accC = fmaf(zv.y, wc_r[q].y, accC);
            accC = fmaf(zv.z, wc_r[q].z, accC);
            accC = fmaf(zv.w, wc_r[q].w, accC);
            accY = fmaf(zv.x, wy_r[q].x, accY);
            accY = fmaf(zv.y, wy_r[q].y, accY);
            accY = fmaf(zv.z, wy_r[q].z, accY);
            accY = fmaf(zv.w, wy_r[q].w, accY);
        }
        E[it] = __builtin_amdgcn_exp2f(-accC * LOG2E);          // e^{-zc}
        F_s[i * H + h] = __builtin_amdgcn_exp2f(-accY * LOG2E); // e^{-zy}
    }
    __syncthreads();   // F_s ready

    // ---- stage B: iterate set bits of the valid mask ----
    float acc[3] = {0.f, 0.f, 0.f};
    unsigned long long bb = bits;
    while (bb) {
        const int jv = __builtin_ctzll(bb);
        bb &= bb - 1;
        const float f = F_s[jv * H + h];   // conflict-free, broadcast half-waves
        #pragma unroll
        for (int it = 0; it < 3; ++it)
            acc[it] += __builtin_amdgcn_rcpf(fmaf(E[it], f, 1.0f));
    }

    // ---- epilogue ----
    const float rden = __builtin_amdgcn_rcpf((float)nvalid);
    float* ob = out + (size_t)b * (NV * H);
    #pragma unroll
    for (int it = 0; it < 3; ++it) {
        const int i = i0 + it * 16;
        ob[i * H + h] = ((bits >> i) & 1ull) ? acc[it] * rden : 0.0f;
    }
}

extern "C" void kernel_launch(void* const* d_in, const int* in_sizes, int n_in,
                              void* d_out, int out_size, void* d_ws, size_t ws_size,
                              hipStream_t stream) {
    const float* z    = (const float*)d_in[0];
    const float* Wc   = (const float*)d_in[1];
    const float* bc   = (const float*)d_in[2];
    const float* Wy   = (const float*)d_in[3];
    const float* by   = (const float*)d_in[4];
    const int*   mask = (const int*)d_in[5];
    float* out = (float*)d_out;

    const int ngraph = in_sizes[0] / (NV * H);   // 512
    OptLinker_attn_kernel<<<ngraph, BLOCK, 0, stream>>>(z, Wc, bc, Wy, by, mask, out);
}

// Round 3
// 11.324 us; speedup vs baseline: 6.4788x; 1.9135x over previous
//
#include <hip/hip_runtime.h>

// out[b,i,h] = m_i * (1/denom_b) * sum_{j valid} sigmoid(zc[b,i,h] + zy[b,j,h])
// zc = z@Wc^T+bc, zy = z@Wy^T+by.
// sigmoid(a+b) = 1/(1+e^{-a}e^{-b}); E=e^{-zc} (regs), F=e^{-zy} (LDS).
// Invalid j: F = 1e8 sentinel -> contribution ~1e-8, so the j-loop is a FIXED
// fully-unrolled 48-trip loop (compile-time LDS offsets, pipelineable).
// 4-way rational combine: 1/t0+1/t1+1/t2+1/t3 = (sum of triple products)/(t0t1t2t3)
// -> one v_rcp per 4 j's. Sentinel keeps all intermediates finite in fp32.

#define LOG2E 1.4426950408889634f

constexpr int NV = 48;
constexpr int H  = 32;
constexpr int BLOCK = 512;      // 8 waves; thread = (i0 in 0..15, h in 0..31)
constexpr int WPAD = 36;        // padded W row stride (floats): 16B-aligned rows,
                                // ds_read_b128 only 4-way conflicted (~free)
constexpr float F_INV = 1.0e8f; // sentinel for invalid j

__global__ __launch_bounds__(BLOCK, 4)
void OptLinker_attn_kernel(const float* __restrict__ z,
                           const float* __restrict__ Wc,
                           const float* __restrict__ bc,
                           const float* __restrict__ Wy,
                           const float* __restrict__ by,
                           const int*   __restrict__ mask,
                           float* __restrict__ out)
{
    __shared__ float z_s[NV * H];       // 6 KB
    __shared__ float F_s[NV * H];       // 6 KB  e^{-zy[j,h]} (or sentinel)
    __shared__ float wc_s[H * WPAD];    // 4.5 KB
    __shared__ float wy_s[H * WPAD];    // 4.5 KB

    const int b   = blockIdx.x;
    const int tid = threadIdx.x;
    const int h   = tid & 31;           // lane's H column
    const int i0  = tid >> 5;           // 0..15; rows i0, i0+16, i0+32

    // ---- stage 0a: z tile -> LDS (float4, coalesced; 384 float4) ----
    const float4* zb4 = (const float4*)(z + (size_t)b * (NV * H));
    if (tid < (NV * H) / 4) ((float4*)z_s)[tid] = zb4[tid];

    // ---- stage 0b: W -> LDS, coalesced, one float4 per thread ----
    {
        const int q = tid & 255;                    // float4 index within matrix
        const float4 v = (tid < 256) ? ((const float4*)Wc)[q]
                                     : ((const float4*)Wy)[q];
        float* dst = (tid < 256 ? wc_s : wy_s) + (q >> 3) * WPAD + (q & 7) * 4;
        *(float4*)dst = v;                          // 16B-aligned (WPAD*4=144, %16==0)
    }

    // ---- stage 0c: valid-j bitmask via ballot (wave-redundant, no LDS) ----
    const int lane = tid & 63;
    const int mv = (lane < NV) ? mask[b * NV + lane] : 0;
    const unsigned long long bits = __ballot(mv != 0);
    const float bcv = bc[h], byv = by[h];

    __syncthreads();   // z_s, W LDS ready

    // ---- W row h -> registers via ds_read_b128 (4-way conflict, ~free) ----
    float4 wc_r[8], wy_r[8];
    {
        const float* wrc = wc_s + h * WPAD;
        const float* wry = wy_s + h * WPAD;
        #pragma unroll
        for (int q = 0; q < 8; ++q) {
            wc_r[q] = *(const float4*)(wrc + q * 4);
            wy_r[q] = *(const float4*)(wry + q * 4);
        }
    }

    // ---- stage A: zc, zy for 3 rows; E in regs, F (or sentinel) to LDS ----
    float E[3];
    #pragma unroll
    for (int it = 0; it < 3; ++it) {
        const int i = i0 + it * 16;
        float accC = bcv, accY = byv;
        const float4* zr = (const float4*)(z_s + i * H);
        #pragma unroll
        for (int q = 0; q < 8; ++q) {
            const float4 zv = zr[q];   // broadcast ds_read_b128
            accC = fmaf(zv.x, wc_r[q].x, accC);
            accC = fmaf(zv.y, wc_r[q].y, accC);
            accC = fmaf(zv.z, wc_r[q].z, accC);
            accC = fmaf(zv.w, wc_r[q].w, accC);
            accY = fmaf(zv.x, wy_r[q].x, accY);
            accY = fmaf(zv.y, wy_r[q].y, accY);
            accY = fmaf(zv.z, wy_r[q].z, accY);
            accY = fmaf(zv.w, wy_r[q].w, accY);
        }
        E[it] = __builtin_amdgcn_exp2f(-accC * LOG2E);           // e^{-zc}
        const bool vi = (bits >> i) & 1ull;
        F_s[i * H + h] = vi ? __builtin_amdgcn_exp2f(-accY * LOG2E) : F_INV;
    }
    __syncthreads();   // F_s ready

    // ---- stage B: fixed 48-trip loop, 4-way rational combine ----
    float acc[3] = {0.f, 0.f, 0.f};
    #pragma unroll
    for (int j = 0; j < NV; j += 4) {
        const float f0 = F_s[(j + 0) * H + h];   // bank h, broadcast: conflict-free
        const float f1 = F_s[(j + 1) * H + h];
        const float f2 = F_s[(j + 2) * H + h];
        const float f3 = F_s[(j + 3) * H + h];
        #pragma unroll
        for (int it = 0; it < 3; ++it) {
            const float Ei = E[it];
            const float t0 = fmaf(Ei, f0, 1.0f);
            const float t1 = fmaf(Ei, f1, 1.0f);
            const float t2 = fmaf(Ei, f2, 1.0f);
            const float t3 = fmaf(Ei, f3, 1.0f);
            const float p01 = t0 * t1, p23 = t2 * t3;
            const float den = p01 * p23;
            const float num = fmaf(t0 + t1, p23, (t2 + t3) * p01);
            acc[it] = fmaf(num, __builtin_amdgcn_rcpf(den), acc[it]);
        }
    }

    // ---- epilogue ----
    const int nvalid = __popcll(bits);
    const float rden = __builtin_amdgcn_rcpf((float)nvalid);
    float* ob = out + (size_t)b * (NV * H);
    #pragma unroll
    for (int it = 0; it < 3; ++it) {
        const int i = i0 + it * 16;
        ob[i * H + h] = ((bits >> i) & 1ull) ? acc[it] * rden : 0.0f;
    }
}

extern "C" void kernel_launch(void* const* d_in, const int* in_sizes, int n_in,
                              void* d_out, int out_size, void* d_ws, size_t ws_size,
                              hipStream_t stream) {
    const float* z    = (const float*)d_in[0];
    const float* Wc   = (const float*)d_in[1];
    const float* bc   = (const float*)d_in[2];
    const float* Wy   = (const float*)d_in[3];
    const float* by   = (const float*)d_in[4];
    const int*   mask = (const int*)d_in[5];
    float* out = (float*)d_out;

    const int ngraph = in_sizes[0] / (NV * H);   // 512
    OptLinker_attn_kernel<<<ngraph, BLOCK, 0, stream>>>(z, Wc, bc, Wy, by, mask, out);
}